// Round 4
// baseline (351.397 us; speedup 1.0000x reference)
//
#include <hip/hip_runtime.h>
#include <hip/hip_cooperative_groups.h>

namespace cg = cooperative_groups;

#define N 12288
#define DIN 128
#define DOUT 64
#define NBIN 8192
#define NCH 384            // chunks of 32 rows
#define NBLK 256
#define NTHR 256
#define NWAVE 1024         // NBLK * NTHR/64

// monotone float -> bin (order-preserving bit transform, top 13 bits)
__device__ __forceinline__ int t_bin(float x) {
    unsigned b = __float_as_uint(x);
    unsigned o = (b & 0x80000000u) ? ~b : (b | 0x80000000u);
    return (int)(o >> 19);
}

struct Args {
    const float* h; const float* W; const float* a;
    float* Wh; float* s; float* t;
    float* tscat; float* tfin;
    float* Vexc; float* Usuf; float* vsexc; float* ussuf;
    float* Vct; float* Uct; float* basevt; float* baseut;
    float* vsc; float* usc; float* basevs; float* baseus;
    int* hist; int* binoff; int* binstart; int* ordarr; int* ordfin;
    float* out;
};

__global__ __launch_bounds__(NTHR) void gat_all(Args A) {
    cg::grid_group grid = cg::this_grid();
    __shared__ float4 sm4[4096];               // 64 KB, reused per phase
    int tid = threadIdx.x, wave = tid >> 6, lane = tid & 63;
    int blk = blockIdx.x;
    int gwave = blk * 4 + wave;

    // ===== Phase A: zero hist+binoff (contiguous 16384 ints) + GEMM =====
    if (tid < 64) ((int*)A.hist)[blk * 64 + tid] = 0;
    if (blk < 192) {                           // 192 tiles x 64 rows
        float4* Ws4 = sm4;                     // W[k][c4]  (32 KB)
        float4* hs4 = sm4 + 2048;              // h[r][k4]  (32 KB)
        const float4* W4 = (const float4*)A.W;
        #pragma unroll
        for (int e = tid; e < 2048; e += NTHR) Ws4[e] = W4[e];
        int row0 = blk * 64;
        const float4* h4 = (const float4*)(A.h + (size_t)row0 * DIN);
        #pragma unroll
        for (int e = tid; e < 2048; e += NTHR) hs4[e] = h4[e];
        __syncthreads();
        int c0 = lane & 15, rq = lane >> 4;
        int rbase = wave * 16 + rq * 4;
        float4 acc[4];
        #pragma unroll
        for (int rr = 0; rr < 4; ++rr) acc[rr] = make_float4(0.f, 0.f, 0.f, 0.f);
        #pragma unroll 2
        for (int kk = 0; kk < 32; ++kk) {
            float4 w0 = Ws4[(4 * kk + 0) * 16 + c0];
            float4 w1 = Ws4[(4 * kk + 1) * 16 + c0];
            float4 w2 = Ws4[(4 * kk + 2) * 16 + c0];
            float4 w3 = Ws4[(4 * kk + 3) * 16 + c0];
            #pragma unroll
            for (int rr = 0; rr < 4; ++rr) {
                float4 hv = hs4[(rbase + rr) * 32 + kk];
                acc[rr].x = fmaf(hv.x, w0.x, acc[rr].x);
                acc[rr].y = fmaf(hv.x, w0.y, acc[rr].y);
                acc[rr].z = fmaf(hv.x, w0.z, acc[rr].z);
                acc[rr].w = fmaf(hv.x, w0.w, acc[rr].w);
                acc[rr].x = fmaf(hv.y, w1.x, acc[rr].x);
                acc[rr].y = fmaf(hv.y, w1.y, acc[rr].y);
                acc[rr].z = fmaf(hv.y, w1.z, acc[rr].z);
                acc[rr].w = fmaf(hv.y, w1.w, acc[rr].w);
                acc[rr].x = fmaf(hv.z, w2.x, acc[rr].x);
                acc[rr].y = fmaf(hv.z, w2.y, acc[rr].y);
                acc[rr].z = fmaf(hv.z, w2.z, acc[rr].z);
                acc[rr].w = fmaf(hv.z, w2.w, acc[rr].w);
                acc[rr].x = fmaf(hv.w, w3.x, acc[rr].x);
                acc[rr].y = fmaf(hv.w, w3.y, acc[rr].y);
                acc[rr].z = fmaf(hv.w, w3.z, acc[rr].z);
                acc[rr].w = fmaf(hv.w, w3.w, acc[rr].w);
            }
        }
        float4 a1 = ((const float4*)A.a)[c0];
        float4 a2 = ((const float4*)A.a)[16 + c0];
        #pragma unroll
        for (int rr = 0; rr < 4; ++rr) {
            int row = row0 + rbase + rr;
            ((float4*)A.Wh)[(size_t)row * 16 + c0] = acc[rr];
            float sv = acc[rr].x * a1.x + acc[rr].y * a1.y + acc[rr].z * a1.z + acc[rr].w * a1.w;
            float tv = acc[rr].x * a2.x + acc[rr].y * a2.y + acc[rr].z * a2.z + acc[rr].w * a2.w;
            #pragma unroll
            for (int off = 8; off; off >>= 1) {
                sv += __shfl_xor(sv, off, 64);
                tv += __shfl_xor(tv, off, 64);
            }
            if (c0 == 0) { A.s[row] = sv; A.t[row] = tv; }
        }
    }
    grid.sync();

    // ===== Phase B: histogram (device-scope atomics, ~2/bin contention) ====
    { int e = blk * NTHR + tid;
      if (e < N) atomicAdd(&A.hist[t_bin(A.t[e])], 1); }
    grid.sync();

    // ===== Phase C: bin exclusive scan (block 0 only) =====
    if (blk == 0) {
        int* wtot = (int*)sm4;
        const int4* h4p = (const int4*)A.hist;
        int csum[32]; int ssum = 0;
        #pragma unroll
        for (int g = 0; g < 8; ++g) {
            int4 q = h4p[tid * 8 + g];
            csum[g * 4 + 0] = ssum; ssum += q.x;
            csum[g * 4 + 1] = ssum; ssum += q.y;
            csum[g * 4 + 2] = ssum; ssum += q.z;
            csum[g * 4 + 3] = ssum; ssum += q.w;
        }
        int inc = ssum;
        #pragma unroll
        for (int off = 1; off < 64; off <<= 1) {
            int nb = __shfl_up(inc, off, 64);
            if (lane >= off) inc += nb;
        }
        if (lane == 63) wtot[wave] = inc;
        __syncthreads();
        int wbase = 0;
        #pragma unroll
        for (int w = 0; w < 4; ++w) wbase += (w < wave) ? wtot[w] : 0;
        int tstart = wbase + inc - ssum;
        #pragma unroll
        for (int e = 0; e < 32; ++e) A.binstart[tid * 32 + e] = tstart + csum[e];
        if (tid == 0) A.binstart[NBIN] = N;
    }
    grid.sync();

    // ===== Phase D: scatter into bin-grouped order =====
    { int e = blk * NTHR + tid;
      if (e < N) {
          float tj = A.t[e];
          int b = t_bin(tj);
          int pos = A.binstart[b] + atomicAdd(&A.binoff[b], 1);
          A.ordarr[pos] = e;
          A.tscat[pos] = tj;
      } }
    grid.sync();

    // ===== Phase E: within-bin exact rank (wave per position) =====
    for (int p = gwave; p < N; p += NWAVE) {
        float tp = A.tscat[p];
        int b = t_bin(tp);
        int lo = A.binstart[b], hi = A.binstart[b + 1];
        int cnt = 0;
        for (int q0 = lo; q0 < hi; q0 += 64) {   // uniform bounds: all lanes active
            int q = q0 + lane;
            bool c = false;
            if (q < hi) {
                float tq = A.tscat[q];
                c = (tq < tp) || (tq == tp && q < p);
            }
            cnt += (int)__popcll(__ballot(c));
        }
        if (lane == 0) {
            A.tfin[lo + cnt] = tp;
            A.ordfin[lo + cnt] = A.ordarr[p];
        }
    }
    grid.sync();

    // ===== Phase F: per-chunk (32 rows) column sums =====
    {
        float* lv  = (float*)sm4;          // [4][64]
        float* lu  = lv + 256;
        float* lsv = lu + 256;             // [4]
        float* lsu = lsv + 4;
        float T = A.tfin[N - 1];
        for (int chunk = blk; chunk < NCH; chunk += NBLK) {
            int r0 = chunk * 32 + wave * 8;
            float av = 0.f, au = 0.f, asv = 0.f, asu = 0.f;
            #pragma unroll
            for (int rr = 0; rr < 8; ++rr) {
                int row = r0 + rr;
                int j = A.ordfin[row];
                float tv = A.tfin[row];
                float u = expf(tv - T);
                float v = expf(0.2f * (tv - T));
                float wv = A.Wh[(size_t)j * DOUT + lane];
                av = fmaf(v, wv, av); au = fmaf(u, wv, au);
                asv += v; asu += u;
            }
            lv[wave * 64 + lane] = av; lu[wave * 64 + lane] = au;
            if (lane == 0) { lsv[wave] = asv; lsu[wave] = asu; }
            __syncthreads();
            if (wave == 0) {
                float sv_ = lv[lane] + lv[64 + lane] + lv[128 + lane] + lv[192 + lane];
                float su_ = lu[lane] + lu[64 + lane] + lu[128 + lane] + lu[192 + lane];
                A.Vct[(size_t)lane * NCH + chunk] = sv_;
                A.Uct[(size_t)lane * NCH + chunk] = su_;
                if (lane == 0) {
                    A.vsc[chunk] = lsv[0] + lsv[1] + lsv[2] + lsv[3];
                    A.usc[chunk] = lsu[0] + lsu[1] + lsu[2] + lsu[3];
                }
            }
            __syncthreads();
        }
    }
    grid.sync();

    // ===== Phase G: scan chunk sums per column (wave per task) =====
    {
        int task = gwave;
        if (task < 130) {
            const float* src; float* dst;
            bool fwd;
            if (task < 64)       { src = A.Vct + (size_t)task * NCH; dst = A.basevt + (size_t)task * NCH; fwd = true; }
            else if (task < 128) { src = A.Uct + (size_t)(task - 64) * NCH; dst = A.baseut + (size_t)(task - 64) * NCH; fwd = false; }
            else if (task == 128){ src = A.vsc; dst = A.basevs; fwd = true; }
            else                 { src = A.usc; dst = A.baseus; fwd = false; }
            float base = 0.f;
            if (fwd) {                               // forward exclusive
                for (int c0 = 0; c0 < NCH; c0 += 64) {
                    float x = src[c0 + lane];
                    float inc = x;
                    #pragma unroll
                    for (int off = 1; off < 64; off <<= 1) {
                        float nb = __shfl_up(inc, off, 64);
                        if (lane >= off) inc += nb;
                    }
                    dst[c0 + lane] = base + inc - x;
                    base += __shfl(inc, 63, 64);
                }
                if (lane == 0) {
                    if (task < 64) {
                        A.Vexc[(size_t)N * DOUT + task] = base;   // column total
                        A.Usuf[(size_t)N * DOUT + task] = 0.f;
                    } else {
                        A.vsexc[N] = base; A.ussuf[N] = 0.f;
                    }
                }
            } else {                                 // suffix exclusive
                for (int c0 = NCH - 64; c0 >= 0; c0 -= 64) {
                    int idx = c0 + (63 - lane);      // lane0 = highest chunk
                    float x = src[idx];
                    float inc = x;
                    #pragma unroll
                    for (int off = 1; off < 64; off <<= 1) {
                        float nb = __shfl_up(inc, off, 64);
                        if (lane >= off) inc += nb;
                    }
                    dst[idx] = base + inc - x;
                    base += __shfl(inc, 63, 64);
                }
            }
        }
    }
    grid.sync();

    // ===== Phase H: apply within-chunk running sums (wave per chunk,V/U) ===
    {
        float T = A.tfin[N - 1];
        int task = gwave;
        if (task < 2 * NCH) {
            int chunk = task >> 1;
            bool isU = task & 1;
            int r0 = chunk * 32;
            float wv[32], wt[32];
            #pragma unroll
            for (int rr = 0; rr < 32; ++rr) {
                int j = A.ordfin[r0 + rr];
                wv[rr] = A.Wh[(size_t)j * DOUT + lane];
                float tv = A.tfin[r0 + rr];
                wt[rr] = isU ? expf(tv - T) : expf(0.2f * (tv - T));
            }
            if (!isU) {                              // V: forward exclusive
                float run  = A.basevt[(size_t)lane * NCH + chunk];
                float runs = A.basevs[chunk];
                #pragma unroll
                for (int rr = 0; rr < 32; ++rr) {
                    int row = r0 + rr;
                    A.Vexc[(size_t)row * DOUT + lane] = run;
                    if (lane == 0) A.vsexc[row] = runs;
                    run = fmaf(wt[rr], wv[rr], run);
                    runs += wt[rr];
                }
            } else {                                 // U: suffix inclusive
                float run  = A.baseut[(size_t)lane * NCH + chunk];
                float runs = A.baseus[chunk];
                #pragma unroll
                for (int rr = 31; rr >= 0; --rr) {
                    int row = r0 + rr;
                    run = fmaf(wt[rr], wv[rr], run);
                    runs += wt[rr];
                    A.Usuf[(size_t)row * DOUT + lane] = run;
                    if (lane == 0) A.ussuf[row] = runs;
                }
            }
        }
    }
    grid.sync();

    // ===== Phase I: bin-seeded binary search + combine + ELU (wave/row) ====
    {
        float T = A.tfin[N - 1];
        for (int i = gwave; i < N; i += NWAVE) {
            float si = A.s[i];
            float thr = -si;
            int b = t_bin(thr);
            int lo = A.binstart[b], hi = A.binstart[b + 1];
            while (lo < hi) {
                int mid = (lo + hi) >> 1;
                if (A.tfin[mid] < thr) lo = mid + 1; else hi = mid;
            }
            int k = lo;
            float x = si + T;
            float m = fmaxf(x, 0.2f * x);
            float cp = expf(x - m);
            float cn = expf(0.2f * x - m);
            float den = cn * A.vsexc[k] + cp * A.ussuf[k];
            float num = cn * A.Vexc[(size_t)k * DOUT + lane]
                      + cp * A.Usuf[(size_t)k * DOUT + lane];
            float r = num / den;
            A.out[(size_t)i * DOUT + lane] = r > 0.f ? r : expm1f(r);
        }
    }
}

extern "C" void kernel_launch(void* const* d_in, const int* in_sizes, int n_in,
                              void* d_out, int out_size, void* d_ws, size_t ws_size,
                              hipStream_t stream) {
    float* ws = (float*)d_ws;
    size_t o = 0;
    Args A;
    A.h = (const float*)d_in[0];
    A.W = (const float*)d_in[1];
    A.a = (const float*)d_in[2];
    A.out = (float*)d_out;
    A.Wh     = ws + o; o += (size_t)N * DOUT;
    A.Vexc   = ws + o; o += (size_t)(N + 1) * DOUT;
    A.Usuf   = ws + o; o += (size_t)(N + 1) * DOUT;
    A.s      = ws + o; o += N;
    A.t      = ws + o; o += N;
    A.tscat  = ws + o; o += N;
    A.tfin   = ws + o; o += N;
    A.vsexc  = ws + o; o += N + 1;
    A.ussuf  = ws + o; o += N + 1;
    o += 2;                                  // keep 16B alignment
    A.Vct    = ws + o; o += (size_t)DOUT * NCH;
    A.Uct    = ws + o; o += (size_t)DOUT * NCH;
    A.basevt = ws + o; o += (size_t)DOUT * NCH;
    A.baseut = ws + o; o += (size_t)DOUT * NCH;
    A.vsc    = ws + o; o += NCH;
    A.usc    = ws + o; o += NCH;
    A.basevs = ws + o; o += NCH;
    A.baseus = ws + o; o += NCH;
    A.hist     = (int*)(ws + o); o += NBIN;      // hist+binoff contiguous
    A.binoff   = (int*)(ws + o); o += NBIN;      //   (zeroed together)
    A.binstart = (int*)(ws + o); o += NBIN + 1;
    A.ordarr   = (int*)(ws + o); o += N;
    A.ordfin   = (int*)(ws + o); o += N;

    void* kargs[] = { (void*)&A };
    hipLaunchCooperativeKernel((void*)gat_all, dim3(NBLK), dim3(NTHR),
                               kargs, 0, stream);
}

// Round 5
// 278.708 us; speedup vs baseline: 1.2608x; 1.2608x over previous
//
#include <hip/hip_runtime.h>

#define N 12288
#define M (2 * N)          // keys (t_j) + queries (-s_i)
#define DIN 128
#define DOUT 64
#define NBIN 4096
#define BSHIFT 20          // 32 - log2(NBIN)
#define NCHUNK 384         // M / 64

// monotone float -> bin (order-preserving bit transform, top 12 bits)
__device__ __forceinline__ int t_bin(float x) {
    unsigned b = __float_as_uint(x);
    unsigned o = (b & 0x80000000u) ? ~b : (b | 0x80000000u);
    return (int)(o >> BSHIFT);
}

struct Args {
    const float *h, *W, *a;
    float *Wh, *s, *t, *tblkmax, *Thdr;
    float *vals, *tfin;
    int *ids, *idfin, *binstart;
    float *Vct, *Uct, *vsc, *usc;
    float *out;
};

// ---------- K1: Wh = h@W, s, t, per-block max(t) (192 blocks) ----------
__global__ __launch_bounds__(256) void k1_gemm(Args A) {
    __shared__ float4 sm4[4096];               // 64 KB
    int tid = threadIdx.x, wave = tid >> 6, lane = tid & 63, blk = blockIdx.x;
    float4* Ws4 = sm4;                         // W[k][c4]
    float4* hs4 = sm4 + 2048;                  // h[r][k4]
    const float4* W4 = (const float4*)A.W;
    for (int e = tid; e < 2048; e += 256) Ws4[e] = W4[e];
    int row0 = blk * 64;
    const float4* h4 = (const float4*)(A.h + (size_t)row0 * DIN);
    for (int e = tid; e < 2048; e += 256) hs4[e] = h4[e];
    __syncthreads();
    int c0 = lane & 15, rq = lane >> 4;
    int rbase = wave * 16 + rq * 4;
    float4 acc[4];
    #pragma unroll
    for (int rr = 0; rr < 4; ++rr) acc[rr] = make_float4(0.f, 0.f, 0.f, 0.f);
    #pragma unroll 2
    for (int kk = 0; kk < 32; ++kk) {
        float4 w0 = Ws4[(4 * kk + 0) * 16 + c0];
        float4 w1 = Ws4[(4 * kk + 1) * 16 + c0];
        float4 w2 = Ws4[(4 * kk + 2) * 16 + c0];
        float4 w3 = Ws4[(4 * kk + 3) * 16 + c0];
        #pragma unroll
        for (int rr = 0; rr < 4; ++rr) {
            float4 hv = hs4[(rbase + rr) * 32 + kk];
            acc[rr].x = fmaf(hv.x, w0.x, acc[rr].x);
            acc[rr].y = fmaf(hv.x, w0.y, acc[rr].y);
            acc[rr].z = fmaf(hv.x, w0.z, acc[rr].z);
            acc[rr].w = fmaf(hv.x, w0.w, acc[rr].w);
            acc[rr].x = fmaf(hv.y, w1.x, acc[rr].x);
            acc[rr].y = fmaf(hv.y, w1.y, acc[rr].y);
            acc[rr].z = fmaf(hv.y, w1.z, acc[rr].z);
            acc[rr].w = fmaf(hv.y, w1.w, acc[rr].w);
            acc[rr].x = fmaf(hv.z, w2.x, acc[rr].x);
            acc[rr].y = fmaf(hv.z, w2.y, acc[rr].y);
            acc[rr].z = fmaf(hv.z, w2.z, acc[rr].z);
            acc[rr].w = fmaf(hv.z, w2.w, acc[rr].w);
            acc[rr].x = fmaf(hv.w, w3.x, acc[rr].x);
            acc[rr].y = fmaf(hv.w, w3.y, acc[rr].y);
            acc[rr].z = fmaf(hv.w, w3.z, acc[rr].z);
            acc[rr].w = fmaf(hv.w, w3.w, acc[rr].w);
        }
    }
    float4 a1 = ((const float4*)A.a)[c0];
    float4 a2 = ((const float4*)A.a)[16 + c0];
    float tmax = -3.4e38f;
    #pragma unroll
    for (int rr = 0; rr < 4; ++rr) {
        int row = row0 + rbase + rr;
        ((float4*)A.Wh)[(size_t)row * 16 + c0] = acc[rr];
        float sv = acc[rr].x * a1.x + acc[rr].y * a1.y + acc[rr].z * a1.z + acc[rr].w * a1.w;
        float tv = acc[rr].x * a2.x + acc[rr].y * a2.y + acc[rr].z * a2.z + acc[rr].w * a2.w;
        #pragma unroll
        for (int off = 8; off; off >>= 1) {     // butterfly within 16-lane group
            sv += __shfl_xor(sv, off, 64);
            tv += __shfl_xor(tv, off, 64);
        }
        if (c0 == 0) { A.s[row] = sv; A.t[row] = tv; }
        tmax = fmaxf(tmax, tv);
    }
    tmax = fmaxf(tmax, __shfl_xor(tmax, 16, 64));
    tmax = fmaxf(tmax, __shfl_xor(tmax, 32, 64));
    __syncthreads();                            // before aliasing sm4
    float* wmax = (float*)sm4;
    if (lane == 0) wmax[wave] = tmax;
    __syncthreads();
    if (tid == 0)
        A.tblkmax[blk] = fmaxf(fmaxf(wmax[0], wmax[1]), fmaxf(wmax[2], wmax[3]));
}

// ---------- K2: LDS hist + pre-hist + scan + T + deterministic scatter ------
// 8 blocks x 1024. Each block builds the FULL histogram (and the histogram of
// items before its slice) redundantly in LDS -> no global atomics anywhere.
__global__ __launch_bounds__(1024) void k2_sort(Args A) {
    __shared__ int hist[NBIN];                  // becomes binstart after scan
    __shared__ int pre[NBIN];                   // becomes scatter slot cursor
    __shared__ int wtot[16];
    __shared__ float fmax_[16];
    int tid = threadIdx.x, lane = tid & 63, wave = tid >> 6, blk = blockIdx.x;
    for (int e = tid; e < NBIN; e += 1024) { hist[e] = 0; pre[e] = 0; }
    __syncthreads();
    for (int e = tid; e < M; e += 1024) {
        float v = (e < N) ? A.t[e] : -A.s[e - N];
        atomicAdd(&hist[t_bin(v)], 1);
    }
    int my0 = blk * 3072;
    for (int e = tid; e < my0; e += 1024) {
        float v = (e < N) ? A.t[e] : -A.s[e - N];
        atomicAdd(&pre[t_bin(v)], 1);
    }
    __syncthreads();
    // exclusive scan of hist (4 bins/thread), in place
    int b0 = tid * 4;
    int c4[4]; int sum = 0;
    #pragma unroll
    for (int g = 0; g < 4; ++g) { c4[g] = sum; sum += hist[b0 + g]; }
    int inc = sum;
    #pragma unroll
    for (int off = 1; off < 64; off <<= 1) {
        int nb = __shfl_up(inc, off, 64);
        if (lane >= off) inc += nb;
    }
    if (lane == 63) wtot[wave] = inc;
    __syncthreads();
    int wbase = 0;
    #pragma unroll
    for (int w = 0; w < 16; ++w) wbase += (w < wave) ? wtot[w] : 0;
    int tstart = wbase + inc - sum;
    #pragma unroll
    for (int g = 0; g < 4; ++g) {
        int bs = tstart + c4[g];
        hist[b0 + g] = bs;                      // binstart (exclusive)
        pre[b0 + g] += bs;                      // slot cursor for scatter
        A.binstart[b0 + g] = bs;                // benign duplicate across blocks
    }
    if (tid == 0 && blk == 0) A.binstart[NBIN] = M;
    // T = max(t) from per-block maxima
    float m = (tid < 192) ? A.tblkmax[tid] : -3.4e38f;
    #pragma unroll
    for (int off = 32; off; off >>= 1) m = fmaxf(m, __shfl_xor(m, off, 64));
    if (lane == 0) fmax_[wave] = m;
    __syncthreads();                            // also fences pre[] before use
    if (tid == 0) {
        float mm = fmax_[0];
        #pragma unroll
        for (int w = 1; w < 16; ++w) mm = fmaxf(mm, fmax_[w]);
        A.Thdr[0] = mm;                         // benign duplicate
    }
    __syncthreads();
    // scatter this block's slice (order within bin arbitrary; K3 re-sorts)
    for (int e = my0 + tid; e < my0 + 3072; e += 1024) {
        float v = (e < N) ? A.t[e] : -A.s[e - N];
        int pos = atomicAdd(&pre[t_bin(v)], 1); // LDS atomic, slots disjoint
        A.vals[pos] = v;
        A.ids[pos] = e;
    }
}

// ---------- K3: exact in-bin rank -> fully sorted (tfin, idfin) ----------
// Total order: (value, priority) with queries before equal-valued keys.
__global__ __launch_bounds__(256) void k3_rank(Args A) {
    int tid = threadIdx.x, wave = tid >> 6, lane = tid & 63;
    int gwave = blockIdx.x * 4 + wave;          // 192 blocks -> 768 waves
    for (int p = gwave; p < M; p += 768) {
        float vp = A.vals[p];
        int idp = A.ids[p];
        int pip = (idp >= N) ? (idp - N) : (idp + N);   // query < key on ties
        int b = t_bin(vp);
        int lo = A.binstart[b], hi = A.binstart[b + 1];
        int cnt = 0;
        for (int q0 = lo; q0 < hi; q0 += 64) {
            int q = q0 + lane;
            bool c = false;
            if (q < hi) {
                float vq = A.vals[q];
                if (vq < vp) c = true;
                else if (vq == vp) {
                    int idq = A.ids[q];
                    int piq = (idq >= N) ? (idq - N) : (idq + N);
                    c = piq < pip;
                }
            }
            cnt += (int)__popcll(__ballot(c));
        }
        if (lane == 0) { A.tfin[lo + cnt] = vp; A.idfin[lo + cnt] = idp; }
    }
}

// ---------- K4: per-chunk (64 sorted items) key-sums ----------
__global__ __launch_bounds__(256) void k4_sums(Args A) {
    int tid = threadIdx.x, wave = tid >> 6, lane = tid & 63;
    int c = blockIdx.x * 4 + wave;              // 96 blocks -> 384 chunks
    float T = A.Thdr[0];
    float myval = A.tfin[c * 64 + lane];
    int myid = A.idfin[c * 64 + lane];
    float av = 0.f, au = 0.f, svs = 0.f, sus = 0.f;
    for (int k = 0; k < 64; ++k) {
        float uval = __shfl(myval, k, 64);      // wave-uniform
        int uid = __shfl(myid, k, 64);
        if (uid < N) {                          // key: accumulate
            float wu = expf(uval - T);
            float wv = expf(0.2f * (uval - T));
            float x = A.Wh[(size_t)uid * DOUT + lane];
            av = fmaf(wv, x, av); au = fmaf(wu, x, au);
            svs += wv; sus += wu;
        }
    }
    A.Vct[c * 64 + lane] = av;
    A.Uct[c * 64 + lane] = au;
    if (lane == 0) { A.vsc[c] = svs; A.usc[c] = sus; }
}

// ---------- K5: redundant chunk-prefix + sweep; queries emit output --------
__global__ __launch_bounds__(256) void k5_apply(Args A) {
    int tid = threadIdx.x, wave = tid >> 6, lane = tid & 63;
    int c = blockIdx.x * 4 + wave;              // 384 chunks
    float T = A.Thdr[0];
    // bases: forward-exclusive over chunks; totals for the U suffix trick
    float bv = 0.f, bu = 0.f, tu = 0.f, bvs = 0.f, bus = 0.f, tus = 0.f;
    for (int cp = 0; cp < NCHUNK; ++cp) {
        float vv = A.Vct[cp * 64 + lane];       // coalesced 256 B
        float uu = A.Uct[cp * 64 + lane];
        float vs_ = A.vsc[cp];                  // broadcast load
        float us_ = A.usc[cp];
        if (cp < c) { bv += vv; bu += uu; bvs += vs_; bus += us_; }
        tu += uu; tus += us_;
    }
    float myval = A.tfin[c * 64 + lane];
    int myid = A.idfin[c * 64 + lane];
    float rv = bv, ru = bu, rvs = bvs, rus = bus;
    for (int k = 0; k < 64; ++k) {
        float uval = __shfl(myval, k, 64);
        int uid = __shfl(myid, k, 64);
        if (uid < N) {                          // key: advance running sums
            float wu = expf(uval - T);
            float wv = expf(0.2f * (uval - T));
            float x = A.Wh[(size_t)uid * DOUT + lane];
            rv = fmaf(wv, x, rv); ru = fmaf(wu, x, ru);
            rvs += wv; rus += wu;
        } else {                                // query: emit output row
            int i = uid - N;
            float si = -uval;                   // value was -s_i
            float x = si + T;
            float mm = fmaxf(x, 0.2f * x);      // lrelu(s_i + T) = row max
            float cp_ = expf(x - mm);
            float cn_ = expf(0.2f * x - mm);
            float num = cn_ * rv + cp_ * (tu - ru);
            float den = cn_ * rvs + cp_ * (tus - rus);
            float r = num / den;
            A.out[(size_t)i * DOUT + lane] = r > 0.f ? r : expm1f(r);
        }
    }
}

extern "C" void kernel_launch(void* const* d_in, const int* in_sizes, int n_in,
                              void* d_out, int out_size, void* d_ws, size_t ws_size,
                              hipStream_t stream) {
    float* ws = (float*)d_ws;
    size_t o = 0;
    Args A;
    A.h = (const float*)d_in[0];
    A.W = (const float*)d_in[1];
    A.a = (const float*)d_in[2];
    A.out = (float*)d_out;
    A.Wh      = ws + o; o += (size_t)N * DOUT;      // float4-aligned (o=0)
    A.s       = ws + o; o += N;
    A.t       = ws + o; o += N;
    A.tblkmax = ws + o; o += 192;
    A.Thdr    = ws + o; o += 16;
    A.vals    = ws + o; o += M;
    A.tfin    = ws + o; o += M;
    A.Vct     = ws + o; o += (size_t)NCHUNK * DOUT;
    A.Uct     = ws + o; o += (size_t)NCHUNK * DOUT;
    A.vsc     = ws + o; o += NCHUNK;
    A.usc     = ws + o; o += NCHUNK;
    A.ids      = (int*)(ws + o); o += M;
    A.idfin    = (int*)(ws + o); o += M;
    A.binstart = (int*)(ws + o); o += NBIN + 1;
    // ~3.8 MB total; no initialization required (no poison-sensitive state)

    k1_gemm <<<N / 64, 256, 0, stream>>>(A);
    k2_sort <<<8, 1024, 0, stream>>>(A);
    k3_rank <<<192, 256, 0, stream>>>(A);
    k4_sums <<<NCHUNK / 4, 256, 0, stream>>>(A);
    k5_apply<<<NCHUNK / 4, 256, 0, stream>>>(A);
}

// Round 6
// 221.912 us; speedup vs baseline: 1.5835x; 1.2559x over previous
//
#include <hip/hip_runtime.h>

#define N 12288
#define M (2 * N)          // keys (t_j) + queries (-s_i)
#define DIN 128
#define DOUT 64
#define NBIN 4096
#define BSHIFT 20          // 32 - log2(NBIN)
#define NCHUNK 384         // M / 64

// monotone float -> bin (order-preserving bit transform, top 12 bits)
__device__ __forceinline__ int t_bin(float x) {
    unsigned b = __float_as_uint(x);
    unsigned o = (b & 0x80000000u) ? ~b : (b | 0x80000000u);
    return (int)(o >> BSHIFT);
}

struct Args {
    const float *h, *W, *a;
    float *Wh, *s, *t, *tblkmax, *Thdr;
    float *vals, *tfin;
    int *ids, *idfin, *binstart;
    float *Vct, *Uct, *vsc, *usc;
    float *basevt, *baseut, *basevs, *baseus, *utot, *utots;
    float *out;
};

// ---------- K1: Wh = h@W, s, t, per-block max(t) (192 blocks) ----------
__global__ __launch_bounds__(256) void k1_gemm(Args A) {
    __shared__ float4 sm4[4096];               // 64 KB
    int tid = threadIdx.x, wave = tid >> 6, lane = tid & 63, blk = blockIdx.x;
    float4* Ws4 = sm4;                         // W[k][c4]
    float4* hs4 = sm4 + 2048;                  // h[r][k4]
    const float4* W4 = (const float4*)A.W;
    for (int e = tid; e < 2048; e += 256) Ws4[e] = W4[e];
    int row0 = blk * 64;
    const float4* h4 = (const float4*)(A.h + (size_t)row0 * DIN);
    for (int e = tid; e < 2048; e += 256) hs4[e] = h4[e];
    __syncthreads();
    int c0 = lane & 15, rq = lane >> 4;
    int rbase = wave * 16 + rq * 4;
    float4 acc[4];
    #pragma unroll
    for (int rr = 0; rr < 4; ++rr) acc[rr] = make_float4(0.f, 0.f, 0.f, 0.f);
    #pragma unroll 2
    for (int kk = 0; kk < 32; ++kk) {
        float4 w0 = Ws4[(4 * kk + 0) * 16 + c0];
        float4 w1 = Ws4[(4 * kk + 1) * 16 + c0];
        float4 w2 = Ws4[(4 * kk + 2) * 16 + c0];
        float4 w3 = Ws4[(4 * kk + 3) * 16 + c0];
        #pragma unroll
        for (int rr = 0; rr < 4; ++rr) {
            float4 hv = hs4[(rbase + rr) * 32 + kk];
            acc[rr].x = fmaf(hv.x, w0.x, acc[rr].x);
            acc[rr].y = fmaf(hv.x, w0.y, acc[rr].y);
            acc[rr].z = fmaf(hv.x, w0.z, acc[rr].z);
            acc[rr].w = fmaf(hv.x, w0.w, acc[rr].w);
            acc[rr].x = fmaf(hv.y, w1.x, acc[rr].x);
            acc[rr].y = fmaf(hv.y, w1.y, acc[rr].y);
            acc[rr].z = fmaf(hv.y, w1.z, acc[rr].z);
            acc[rr].w = fmaf(hv.y, w1.w, acc[rr].w);
            acc[rr].x = fmaf(hv.z, w2.x, acc[rr].x);
            acc[rr].y = fmaf(hv.z, w2.y, acc[rr].y);
            acc[rr].z = fmaf(hv.z, w2.z, acc[rr].z);
            acc[rr].w = fmaf(hv.z, w2.w, acc[rr].w);
            acc[rr].x = fmaf(hv.w, w3.x, acc[rr].x);
            acc[rr].y = fmaf(hv.w, w3.y, acc[rr].y);
            acc[rr].z = fmaf(hv.w, w3.z, acc[rr].z);
            acc[rr].w = fmaf(hv.w, w3.w, acc[rr].w);
        }
    }
    float4 a1 = ((const float4*)A.a)[c0];
    float4 a2 = ((const float4*)A.a)[16 + c0];
    float tmax = -3.4e38f;
    #pragma unroll
    for (int rr = 0; rr < 4; ++rr) {
        int row = row0 + rbase + rr;
        ((float4*)A.Wh)[(size_t)row * 16 + c0] = acc[rr];
        float sv = acc[rr].x * a1.x + acc[rr].y * a1.y + acc[rr].z * a1.z + acc[rr].w * a1.w;
        float tv = acc[rr].x * a2.x + acc[rr].y * a2.y + acc[rr].z * a2.z + acc[rr].w * a2.w;
        #pragma unroll
        for (int off = 8; off; off >>= 1) {
            sv += __shfl_xor(sv, off, 64);
            tv += __shfl_xor(tv, off, 64);
        }
        if (c0 == 0) { A.s[row] = sv; A.t[row] = tv; }
        tmax = fmaxf(tmax, tv);
    }
    tmax = fmaxf(tmax, __shfl_xor(tmax, 16, 64));
    tmax = fmaxf(tmax, __shfl_xor(tmax, 32, 64));
    __syncthreads();
    float* wmax = (float*)sm4;
    if (lane == 0) wmax[wave] = tmax;
    __syncthreads();
    if (tid == 0)
        A.tblkmax[blk] = fmaxf(fmaxf(wmax[0], wmax[1]), fmaxf(wmax[2], wmax[3]));
}

// ---------- K2: LDS hist + pre-hist + scan + T + deterministic scatter ------
// 24 blocks x 1024; slice = 1024 items/block. Full histogram (and before-slice
// histogram) built redundantly in LDS -> no global atomics anywhere.
__global__ __launch_bounds__(1024) void k2_sort(Args A) {
    __shared__ int hist[NBIN];
    __shared__ int pre[NBIN];
    __shared__ int wtot[16];
    __shared__ float fmax_[16];
    int tid = threadIdx.x, lane = tid & 63, wave = tid >> 6, blk = blockIdx.x;
    #pragma unroll
    for (int e = tid; e < NBIN; e += 1024) { hist[e] = 0; pre[e] = 0; }
    __syncthreads();
    #pragma unroll 4
    for (int e = tid; e < M; e += 1024) {
        float v = (e < N) ? A.t[e] : -A.s[e - N];
        atomicAdd(&hist[t_bin(v)], 1);
    }
    int my0 = blk * 1024;
    #pragma unroll 4
    for (int e = tid; e < my0; e += 1024) {
        float v = (e < N) ? A.t[e] : -A.s[e - N];
        atomicAdd(&pre[t_bin(v)], 1);
    }
    __syncthreads();
    int b0 = tid * 4;
    int c4[4]; int sum = 0;
    #pragma unroll
    for (int g = 0; g < 4; ++g) { c4[g] = sum; sum += hist[b0 + g]; }
    int inc = sum;
    #pragma unroll
    for (int off = 1; off < 64; off <<= 1) {
        int nb = __shfl_up(inc, off, 64);
        if (lane >= off) inc += nb;
    }
    if (lane == 63) wtot[wave] = inc;
    __syncthreads();
    int wbase = 0;
    #pragma unroll
    for (int w = 0; w < 16; ++w) wbase += (w < wave) ? wtot[w] : 0;
    int tstart = wbase + inc - sum;
    #pragma unroll
    for (int g = 0; g < 4; ++g) {
        int bs = tstart + c4[g];
        hist[b0 + g] = bs;
        pre[b0 + g] += bs;
        A.binstart[b0 + g] = bs;                // benign duplicate across blocks
    }
    if (tid == 0 && blk == 0) A.binstart[NBIN] = M;
    float m = (tid < 192) ? A.tblkmax[tid] : -3.4e38f;
    #pragma unroll
    for (int off = 32; off; off >>= 1) m = fmaxf(m, __shfl_xor(m, off, 64));
    if (lane == 0) fmax_[wave] = m;
    __syncthreads();
    if (tid == 0) {
        float mm = fmax_[0];
        #pragma unroll
        for (int w = 1; w < 16; ++w) mm = fmaxf(mm, fmax_[w]);
        A.Thdr[0] = mm;
    }
    __syncthreads();
    {   // exactly one item per thread (slice == blockDim)
        int e = my0 + tid;
        float v = (e < N) ? A.t[e] : -A.s[e - N];
        int pos = atomicAdd(&pre[t_bin(v)], 1);
        A.vals[pos] = v;
        A.ids[pos] = e;
    }
}

// ---------- K3: exact in-bin rank -> fully sorted (tfin, idfin) ----------
__global__ __launch_bounds__(256) void k3_rank(Args A) {
    int tid = threadIdx.x, wave = tid >> 6, lane = tid & 63;
    int gwave = blockIdx.x * 4 + wave;          // 192 blocks -> 768 waves
    for (int p = gwave; p < M; p += 768) {
        float vp = A.vals[p];
        int idp = A.ids[p];
        int pip = (idp >= N) ? (idp - N) : (idp + N);   // query < key on ties
        int b = t_bin(vp);
        int lo = A.binstart[b], hi = A.binstart[b + 1];
        int cnt = 0;
        for (int q0 = lo; q0 < hi; q0 += 64) {
            int q = q0 + lane;
            bool c = false;
            if (q < hi) {
                float vq = A.vals[q];
                if (vq < vp) c = true;
                else if (vq == vp) {
                    int idq = A.ids[q];
                    int piq = (idq >= N) ? (idq - N) : (idq + N);
                    c = piq < pip;
                }
            }
            cnt += (int)__popcll(__ballot(c));
        }
        if (lane == 0) { A.tfin[lo + cnt] = vp; A.idfin[lo + cnt] = idp; }
    }
}

// ---------- K4: per-chunk (64 sorted items) key-sums, prefetched gather -----
__global__ __launch_bounds__(256) void k4_sums(Args A) {
    int tid = threadIdx.x, wave = tid >> 6, lane = tid & 63;
    int c = blockIdx.x * 4 + wave;              // 96 blocks -> 384 chunks
    float T = A.Thdr[0];
    float myval = A.tfin[c * 64 + lane];
    int myid = A.idfin[c * 64 + lane];
    float x[64];
    #pragma unroll
    for (int k = 0; k < 64; ++k) {              // 64 independent gathers
        int uid = __shfl(myid, k, 64);
        x[k] = (uid < N) ? A.Wh[(size_t)uid * DOUT + lane] : 0.f;
    }
    float av = 0.f, au = 0.f, svs = 0.f, sus = 0.f;
    #pragma unroll
    for (int k = 0; k < 64; ++k) {
        int uid = __shfl(myid, k, 64);
        if (uid < N) {
            float uval = __shfl(myval, k, 64);
            float wu = expf(uval - T);
            float wv = expf(0.2f * (uval - T));
            av = fmaf(wv, x[k], av); au = fmaf(wu, x[k], au);
            svs += wv; sus += wu;
        }
    }
    A.Vct[c * 64 + lane] = av;
    A.Uct[c * 64 + lane] = au;
    if (lane == 0) { A.vsc[c] = svs; A.usc[c] = sus; }
}

// ---------- K4b: wave-parallel forward-exclusive scans over chunks ----------
// tasks: 0..63 V cols, 64..127 U cols (also emit column totals), 128 vsc,
// 129 usc (emit total). 33 blocks x 256 = 132 waves.
__global__ __launch_bounds__(256) void k4b_scan(Args A) {
    int tid = threadIdx.x, wave = tid >> 6, lane = tid & 63;
    int task = blockIdx.x * 4 + wave;
    if (task >= 130) return;
    const float* src; float* dst; int stride, col = 0;
    if (task < 64)       { col = task;      src = A.Vct; dst = A.basevt; stride = 64; }
    else if (task < 128) { col = task - 64; src = A.Uct; dst = A.baseut; stride = 64; }
    else if (task == 128){ src = A.vsc; dst = A.basevs; stride = 1; }
    else                 { src = A.usc; dst = A.baseus; stride = 1; }
    float base = 0.f;
    for (int c0 = 0; c0 < NCHUNK; c0 += 64) {
        float xv = src[(c0 + lane) * stride + col];
        float inc = xv;
        #pragma unroll
        for (int off = 1; off < 64; off <<= 1) {
            float nb = __shfl_up(inc, off, 64);
            if (lane >= off) inc += nb;
        }
        dst[(c0 + lane) * stride + col] = base + inc - xv;
        base += __shfl(inc, 63, 64);
    }
    if (lane == 0) {
        if (task >= 64 && task < 128) A.utot[col] = base;   // U column total
        else if (task == 129)         A.utots[0] = base;    // U scalar total
    }
}

// ---------- K5: sweep with precomputed bases; queries emit output ----------
__global__ __launch_bounds__(256) void k5_apply(Args A) {
    int tid = threadIdx.x, wave = tid >> 6, lane = tid & 63;
    int c = blockIdx.x * 4 + wave;              // 384 chunks
    float T = A.Thdr[0];
    float myval = A.tfin[c * 64 + lane];
    int myid = A.idfin[c * 64 + lane];
    float x[64];
    #pragma unroll
    for (int k = 0; k < 64; ++k) {              // 64 independent gathers
        int uid = __shfl(myid, k, 64);
        x[k] = (uid < N) ? A.Wh[(size_t)uid * DOUT + lane] : 0.f;
    }
    float rv  = A.basevt[c * 64 + lane];
    float ru  = A.baseut[c * 64 + lane];
    float rvs = A.basevs[c];
    float rus = A.baseus[c];
    float tu  = A.utot[lane];
    float tus = A.utots[0];
    #pragma unroll
    for (int k = 0; k < 64; ++k) {
        float uval = __shfl(myval, k, 64);
        int uid = __shfl(myid, k, 64);
        if (uid < N) {                          // key: advance running sums
            float wu = expf(uval - T);
            float wv = expf(0.2f * (uval - T));
            rv = fmaf(wv, x[k], rv); ru = fmaf(wu, x[k], ru);
            rvs += wv; rus += wu;
        } else {                                // query: emit output row
            int i = uid - N;
            float si = -uval;
            float xx = si + T;
            float mm = fmaxf(xx, 0.2f * xx);
            float cp_ = expf(xx - mm);
            float cn_ = expf(0.2f * xx - mm);
            float num = cn_ * rv + cp_ * (tu - ru);
            float den = cn_ * rvs + cp_ * (tus - rus);
            float r = num / den;
            A.out[(size_t)i * DOUT + lane] = r > 0.f ? r : expm1f(r);
        }
    }
}

extern "C" void kernel_launch(void* const* d_in, const int* in_sizes, int n_in,
                              void* d_out, int out_size, void* d_ws, size_t ws_size,
                              hipStream_t stream) {
    float* ws = (float*)d_ws;
    size_t o = 0;
    Args A;
    A.h = (const float*)d_in[0];
    A.W = (const float*)d_in[1];
    A.a = (const float*)d_in[2];
    A.out = (float*)d_out;
    A.Wh      = ws + o; o += (size_t)N * DOUT;
    A.s       = ws + o; o += N;
    A.t       = ws + o; o += N;
    A.tblkmax = ws + o; o += 192;
    A.Thdr    = ws + o; o += 16;
    A.vals    = ws + o; o += M;
    A.tfin    = ws + o; o += M;
    A.Vct     = ws + o; o += (size_t)NCHUNK * DOUT;
    A.Uct     = ws + o; o += (size_t)NCHUNK * DOUT;
    A.vsc     = ws + o; o += NCHUNK;
    A.usc     = ws + o; o += NCHUNK;
    A.basevt  = ws + o; o += (size_t)NCHUNK * DOUT;
    A.baseut  = ws + o; o += (size_t)NCHUNK * DOUT;
    A.basevs  = ws + o; o += NCHUNK;
    A.baseus  = ws + o; o += NCHUNK;
    A.utot    = ws + o; o += DOUT;
    A.utots   = ws + o; o += 16;
    A.ids      = (int*)(ws + o); o += M;
    A.idfin    = (int*)(ws + o); o += M;
    A.binstart = (int*)(ws + o); o += NBIN + 1;
    // ~4.2 MB total; no initialization required

    k1_gemm <<<N / 64, 256, 0, stream>>>(A);
    k2_sort <<<24, 1024, 0, stream>>>(A);
    k3_rank <<<192, 256, 0, stream>>>(A);
    k4_sums <<<NCHUNK / 4, 256, 0, stream>>>(A);
    k4b_scan<<<33, 256, 0, stream>>>(A);
    k5_apply<<<NCHUNK / 4, 256, 0, stream>>>(A);
}

// Round 7
// 169.248 us; speedup vs baseline: 2.0762x; 1.3112x over previous
//
#include <hip/hip_runtime.h>

#define N 12288
#define M (2 * N)          // keys (t_j) + queries (-s_i)
#define DIN 128
#define DOUT 64
#define NBIN 8192
#define BSHIFT 19          // 32 - log2(NBIN)
#define NCHUNK 384         // M / 64

// monotone float -> bin (order-preserving bit transform, top 13 bits)
__device__ __forceinline__ int t_bin(float x) {
    unsigned b = __float_as_uint(x);
    unsigned o = (b & 0x80000000u) ? ~b : (b | 0x80000000u);
    return (int)(o >> BSHIFT);
}

struct Args {
    const float *h, *W, *a;
    float *Wh, *s, *t, *tblkmax, *Thdr;
    float *vals, *tfin;
    int *ids, *idfin, *binstart;
    float *Vct, *Uct, *vsc, *usc;
    float *basevt, *baseut, *basevs, *baseus, *utot, *utots;
    float *out;
};

// ---------- K1: Wh = h@W, s, t, per-block max(t) (192 blocks) ----------
__global__ __launch_bounds__(256) void k1_gemm(Args A) {
    __shared__ float4 sm4[4096];               // 64 KB
    int tid = threadIdx.x, wave = tid >> 6, lane = tid & 63, blk = blockIdx.x;
    float4* Ws4 = sm4;                         // W[k][c4]
    float4* hs4 = sm4 + 2048;                  // h[r][k4]
    const float4* W4 = (const float4*)A.W;
    for (int e = tid; e < 2048; e += 256) Ws4[e] = W4[e];
    int row0 = blk * 64;
    const float4* h4 = (const float4*)(A.h + (size_t)row0 * DIN);
    for (int e = tid; e < 2048; e += 256) hs4[e] = h4[e];
    __syncthreads();
    int c0 = lane & 15, rq = lane >> 4;
    int rbase = wave * 16 + rq * 4;
    float4 acc[4];
    #pragma unroll
    for (int rr = 0; rr < 4; ++rr) acc[rr] = make_float4(0.f, 0.f, 0.f, 0.f);
    #pragma unroll 2
    for (int kk = 0; kk < 32; ++kk) {
        float4 w0 = Ws4[(4 * kk + 0) * 16 + c0];
        float4 w1 = Ws4[(4 * kk + 1) * 16 + c0];
        float4 w2 = Ws4[(4 * kk + 2) * 16 + c0];
        float4 w3 = Ws4[(4 * kk + 3) * 16 + c0];
        #pragma unroll
        for (int rr = 0; rr < 4; ++rr) {
            float4 hv = hs4[(rbase + rr) * 32 + kk];
            acc[rr].x = fmaf(hv.x, w0.x, acc[rr].x);
            acc[rr].y = fmaf(hv.x, w0.y, acc[rr].y);
            acc[rr].z = fmaf(hv.x, w0.z, acc[rr].z);
            acc[rr].w = fmaf(hv.x, w0.w, acc[rr].w);
            acc[rr].x = fmaf(hv.y, w1.x, acc[rr].x);
            acc[rr].y = fmaf(hv.y, w1.y, acc[rr].y);
            acc[rr].z = fmaf(hv.y, w1.z, acc[rr].z);
            acc[rr].w = fmaf(hv.y, w1.w, acc[rr].w);
            acc[rr].x = fmaf(hv.z, w2.x, acc[rr].x);
            acc[rr].y = fmaf(hv.z, w2.y, acc[rr].y);
            acc[rr].z = fmaf(hv.z, w2.z, acc[rr].z);
            acc[rr].w = fmaf(hv.z, w2.w, acc[rr].w);
            acc[rr].x = fmaf(hv.w, w3.x, acc[rr].x);
            acc[rr].y = fmaf(hv.w, w3.y, acc[rr].y);
            acc[rr].z = fmaf(hv.w, w3.z, acc[rr].z);
            acc[rr].w = fmaf(hv.w, w3.w, acc[rr].w);
        }
    }
    float4 a1 = ((const float4*)A.a)[c0];
    float4 a2 = ((const float4*)A.a)[16 + c0];
    float tmax = -3.4e38f;
    #pragma unroll
    for (int rr = 0; rr < 4; ++rr) {
        int row = row0 + rbase + rr;
        ((float4*)A.Wh)[(size_t)row * 16 + c0] = acc[rr];
        float sv = acc[rr].x * a1.x + acc[rr].y * a1.y + acc[rr].z * a1.z + acc[rr].w * a1.w;
        float tv = acc[rr].x * a2.x + acc[rr].y * a2.y + acc[rr].z * a2.z + acc[rr].w * a2.w;
        #pragma unroll
        for (int off = 8; off; off >>= 1) {
            sv += __shfl_xor(sv, off, 64);
            tv += __shfl_xor(tv, off, 64);
        }
        if (c0 == 0) { A.s[row] = sv; A.t[row] = tv; }
        tmax = fmaxf(tmax, tv);
    }
    tmax = fmaxf(tmax, __shfl_xor(tmax, 16, 64));
    tmax = fmaxf(tmax, __shfl_xor(tmax, 32, 64));
    __syncthreads();
    float* wmax = (float*)sm4;
    if (lane == 0) wmax[wave] = tmax;
    __syncthreads();
    if (tid == 0)
        A.tblkmax[blk] = fmaxf(fmaxf(wmax[0], wmax[1]), fmaxf(wmax[2], wmax[3]));
}

// ---------- K2: LDS hist + pre-hist + scan + T + deterministic scatter ------
// 24 blocks x 1024; slice = 1024 items/block. Full histogram (and before-slice
// histogram) built redundantly in LDS -> no global atomics anywhere.
__global__ __launch_bounds__(1024) void k2_sort(Args A) {
    __shared__ int hist[NBIN];                  // 32 KB
    __shared__ int pre[NBIN];                   // 32 KB
    __shared__ int wtot[16];
    __shared__ float fmax_[16];
    int tid = threadIdx.x, lane = tid & 63, wave = tid >> 6, blk = blockIdx.x;
    #pragma unroll
    for (int e = tid; e < NBIN; e += 1024) { hist[e] = 0; pre[e] = 0; }
    __syncthreads();
    #pragma unroll 4
    for (int e = tid; e < M; e += 1024) {
        float v = (e < N) ? A.t[e] : -A.s[e - N];
        atomicAdd(&hist[t_bin(v)], 1);
    }
    int my0 = blk * 1024;
    #pragma unroll 4
    for (int e = tid; e < my0; e += 1024) {
        float v = (e < N) ? A.t[e] : -A.s[e - N];
        atomicAdd(&pre[t_bin(v)], 1);
    }
    __syncthreads();
    int b0 = tid * 8;
    int c8[8]; int sum = 0;
    #pragma unroll
    for (int g = 0; g < 8; ++g) { c8[g] = sum; sum += hist[b0 + g]; }
    int inc = sum;
    #pragma unroll
    for (int off = 1; off < 64; off <<= 1) {
        int nb = __shfl_up(inc, off, 64);
        if (lane >= off) inc += nb;
    }
    if (lane == 63) wtot[wave] = inc;
    __syncthreads();
    int wbase = 0;
    #pragma unroll
    for (int w = 0; w < 16; ++w) wbase += (w < wave) ? wtot[w] : 0;
    int tstart = wbase + inc - sum;
    #pragma unroll
    for (int g = 0; g < 8; ++g) {
        int bs = tstart + c8[g];
        hist[b0 + g] = bs;
        pre[b0 + g] += bs;
        A.binstart[b0 + g] = bs;                // benign duplicate across blocks
    }
    if (tid == 0 && blk == 0) A.binstart[NBIN] = M;
    float m = (tid < 192) ? A.tblkmax[tid] : -3.4e38f;
    #pragma unroll
    for (int off = 32; off; off >>= 1) m = fmaxf(m, __shfl_xor(m, off, 64));
    if (lane == 0) fmax_[wave] = m;
    __syncthreads();
    if (tid == 0) {
        float mm = fmax_[0];
        #pragma unroll
        for (int w = 1; w < 16; ++w) mm = fmaxf(mm, fmax_[w]);
        A.Thdr[0] = mm;
    }
    __syncthreads();
    {   // exactly one item per thread (slice == blockDim)
        int e = my0 + tid;
        float v = (e < N) ? A.t[e] : -A.s[e - N];
        int pos = atomicAdd(&pre[t_bin(v)], 1);
        A.vals[pos] = v;
        A.ids[pos] = e;
    }
}

// ---------- K3: exact in-bin rank, THREAD per position ----------
// 96 blocks x 256 = 24576 threads = M. Adjacent positions share a bin, so
// inner-loop loads are wave-uniform broadcasts (L1-hit).
__global__ __launch_bounds__(256) void k3_rank(Args A) {
    int p = blockIdx.x * 256 + threadIdx.x;
    float vp = A.vals[p];
    int idp = A.ids[p];
    int pip = (idp >= N) ? (idp - N) : (idp + N);   // query < key on ties
    int b = t_bin(vp);
    int lo = A.binstart[b], hi = A.binstart[b + 1];
    int cnt = 0;
    for (int q = lo; q < hi; ++q) {
        float vq = A.vals[q];
        bool c = false;
        if (vq < vp) c = true;
        else if (vq == vp) {
            int idq = A.ids[q];
            int piq = (idq >= N) ? (idq - N) : (idq + N);
            c = piq < pip;
        }
        cnt += (int)c;
    }
    A.tfin[lo + cnt] = vp;
    A.idfin[lo + cnt] = idp;
}

// ---------- K4: per-chunk (64 sorted items) key-sums, prefetched gather -----
__global__ __launch_bounds__(256) void k4_sums(Args A) {
    int tid = threadIdx.x, wave = tid >> 6, lane = tid & 63;
    int c = blockIdx.x * 4 + wave;              // 96 blocks -> 384 chunks
    float T = A.Thdr[0];
    float myval = A.tfin[c * 64 + lane];
    int myid = A.idfin[c * 64 + lane];
    float x[64];
    #pragma unroll
    for (int k = 0; k < 64; ++k) {              // 64 independent gathers
        int uid = __shfl(myid, k, 64);
        x[k] = (uid < N) ? A.Wh[(size_t)uid * DOUT + lane] : 0.f;
    }
    float av = 0.f, au = 0.f, svs = 0.f, sus = 0.f;
    #pragma unroll
    for (int k = 0; k < 64; ++k) {
        int uid = __shfl(myid, k, 64);
        if (uid < N) {
            float uval = __shfl(myval, k, 64);
            float wu = expf(uval - T);
            float wv = expf(0.2f * (uval - T));
            av = fmaf(wv, x[k], av); au = fmaf(wu, x[k], au);
            svs += wv; sus += wu;
        }
    }
    A.Vct[c * 64 + lane] = av;
    A.Uct[c * 64 + lane] = au;
    if (lane == 0) { A.vsc[c] = svs; A.usc[c] = sus; }
}

// ---------- K4b: wave-parallel forward-exclusive scans over chunks ----------
__global__ __launch_bounds__(256) void k4b_scan(Args A) {
    int tid = threadIdx.x, wave = tid >> 6, lane = tid & 63;
    int task = blockIdx.x * 4 + wave;           // 33 blocks -> 132 waves
    if (task >= 130) return;
    const float* src; float* dst; int stride, col = 0;
    if (task < 64)       { col = task;      src = A.Vct; dst = A.basevt; stride = 64; }
    else if (task < 128) { col = task - 64; src = A.Uct; dst = A.baseut; stride = 64; }
    else if (task == 128){ src = A.vsc; dst = A.basevs; stride = 1; }
    else                 { src = A.usc; dst = A.baseus; stride = 1; }
    float base = 0.f;
    for (int c0 = 0; c0 < NCHUNK; c0 += 64) {
        float xv = src[(c0 + lane) * stride + col];
        float inc = xv;
        #pragma unroll
        for (int off = 1; off < 64; off <<= 1) {
            float nb = __shfl_up(inc, off, 64);
            if (lane >= off) inc += nb;
        }
        dst[(c0 + lane) * stride + col] = base + inc - xv;
        base += __shfl(inc, 63, 64);
    }
    if (lane == 0) {
        if (task >= 64 && task < 128) A.utot[col] = base;   // U column total
        else if (task == 129)         A.utots[0] = base;    // U scalar total
    }
}

// ---------- K5: sweep with precomputed bases; queries emit output ----------
__global__ __launch_bounds__(256) void k5_apply(Args A) {
    int tid = threadIdx.x, wave = tid >> 6, lane = tid & 63;
    int c = blockIdx.x * 4 + wave;              // 384 chunks
    float T = A.Thdr[0];
    float myval = A.tfin[c * 64 + lane];
    int myid = A.idfin[c * 64 + lane];
    float x[64];
    #pragma unroll
    for (int k = 0; k < 64; ++k) {              // 64 independent gathers
        int uid = __shfl(myid, k, 64);
        x[k] = (uid < N) ? A.Wh[(size_t)uid * DOUT + lane] : 0.f;
    }
    float rv  = A.basevt[c * 64 + lane];
    float ru  = A.baseut[c * 64 + lane];
    float rvs = A.basevs[c];
    float rus = A.baseus[c];
    float tu  = A.utot[lane];
    float tus = A.utots[0];
    #pragma unroll
    for (int k = 0; k < 64; ++k) {
        float uval = __shfl(myval, k, 64);
        int uid = __shfl(myid, k, 64);
        if (uid < N) {                          // key: advance running sums
            float wu = expf(uval - T);
            float wv = expf(0.2f * (uval - T));
            rv = fmaf(wv, x[k], rv); ru = fmaf(wu, x[k], ru);
            rvs += wv; rus += wu;
        } else {                                // query: emit output row
            int i = uid - N;
            float si = -uval;
            float xx = si + T;
            float mm = fmaxf(xx, 0.2f * xx);
            float cp_ = expf(xx - mm);
            float cn_ = expf(0.2f * xx - mm);
            float num = cn_ * rv + cp_ * (tu - ru);
            float den = cn_ * rvs + cp_ * (tus - rus);
            float r = num / den;
            A.out[(size_t)i * DOUT + lane] = r > 0.f ? r : expm1f(r);
        }
    }
}

extern "C" void kernel_launch(void* const* d_in, const int* in_sizes, int n_in,
                              void* d_out, int out_size, void* d_ws, size_t ws_size,
                              hipStream_t stream) {
    float* ws = (float*)d_ws;
    size_t o = 0;
    Args A;
    A.h = (const float*)d_in[0];
    A.W = (const float*)d_in[1];
    A.a = (const float*)d_in[2];
    A.out = (float*)d_out;
    A.Wh      = ws + o; o += (size_t)N * DOUT;
    A.s       = ws + o; o += N;
    A.t       = ws + o; o += N;
    A.tblkmax = ws + o; o += 192;
    A.Thdr    = ws + o; o += 16;
    A.vals    = ws + o; o += M;
    A.tfin    = ws + o; o += M;
    A.Vct     = ws + o; o += (size_t)NCHUNK * DOUT;
    A.Uct     = ws + o; o += (size_t)NCHUNK * DOUT;
    A.vsc     = ws + o; o += NCHUNK;
    A.usc     = ws + o; o += NCHUNK;
    A.basevt  = ws + o; o += (size_t)NCHUNK * DOUT;
    A.baseut  = ws + o; o += (size_t)NCHUNK * DOUT;
    A.basevs  = ws + o; o += NCHUNK;
    A.baseus  = ws + o; o += NCHUNK;
    A.utot    = ws + o; o += DOUT;
    A.utots   = ws + o; o += 16;
    A.ids      = (int*)(ws + o); o += M;
    A.idfin    = (int*)(ws + o); o += M;
    A.binstart = (int*)(ws + o); o += NBIN + 1;
    // ~4.3 MB total; no initialization required

    k1_gemm <<<N / 64, 256, 0, stream>>>(A);
    k2_sort <<<24, 1024, 0, stream>>>(A);
    k3_rank <<<M / 256, 256, 0, stream>>>(A);
    k4_sums <<<NCHUNK / 4, 256, 0, stream>>>(A);
    k4b_scan<<<33, 256, 0, stream>>>(A);
    k5_apply<<<NCHUNK / 4, 256, 0, stream>>>(A);
}

// Round 8
// 137.019 us; speedup vs baseline: 2.5646x; 1.2352x over previous
//
#include <hip/hip_runtime.h>

#define N 12288
#define M (2 * N)          // keys (t_j) + queries (-s_i)
#define DIN 128
#define DOUT 64
#define NBIN 8192
#define BSHIFT 19          // 32 - log2(NBIN)
#define NCHUNK 384         // M / 64

// monotone float -> ordered u32 (order-preserving bit transform)
__device__ __forceinline__ unsigned f_ord(float x) {
    unsigned b = __float_as_uint(x);
    return (b & 0x80000000u) ? ~b : (b | 0x80000000u);
}
__device__ __forceinline__ float ord_f(unsigned u) {
    unsigned b = (u & 0x80000000u) ? (u & 0x7FFFFFFFu) : ~u;
    return __uint_as_float(b);
}
__device__ __forceinline__ int t_bin(float x) { return (int)(f_ord(x) >> BSHIFT); }

struct Args {
    const float *h, *W, *a;
    float *Wh, *s, *t, *tblkmax, *Thdr;
    unsigned long long *vals64;     // (ordered(val)<<32)|pi — unique total order
    float *tfin;
    int *idfin, *binstart;
    float *Vct, *Uct, *vsc, *usc;
    float *basevt, *baseut, *basevs, *baseus, *utot, *utots;
    float *out;
};

// ---------- K1: Wh = h@W, s, t, per-block max(t) (192 blocks) ----------
__global__ __launch_bounds__(256) void k1_gemm(Args A) {
    __shared__ float4 sm4[4096];               // 64 KB
    int tid = threadIdx.x, wave = tid >> 6, lane = tid & 63, blk = blockIdx.x;
    float4* Ws4 = sm4;                         // W[k][c4]
    float4* hs4 = sm4 + 2048;                  // h[r][k4]
    const float4* W4 = (const float4*)A.W;
    for (int e = tid; e < 2048; e += 256) Ws4[e] = W4[e];
    int row0 = blk * 64;
    const float4* h4 = (const float4*)(A.h + (size_t)row0 * DIN);
    for (int e = tid; e < 2048; e += 256) hs4[e] = h4[e];
    __syncthreads();
    int c0 = lane & 15, rq = lane >> 4;
    int rbase = wave * 16 + rq * 4;
    float4 acc[4];
    #pragma unroll
    for (int rr = 0; rr < 4; ++rr) acc[rr] = make_float4(0.f, 0.f, 0.f, 0.f);
    #pragma unroll 2
    for (int kk = 0; kk < 32; ++kk) {
        float4 w0 = Ws4[(4 * kk + 0) * 16 + c0];
        float4 w1 = Ws4[(4 * kk + 1) * 16 + c0];
        float4 w2 = Ws4[(4 * kk + 2) * 16 + c0];
        float4 w3 = Ws4[(4 * kk + 3) * 16 + c0];
        #pragma unroll
        for (int rr = 0; rr < 4; ++rr) {
            float4 hv = hs4[(rbase + rr) * 32 + kk];
            acc[rr].x = fmaf(hv.x, w0.x, acc[rr].x);
            acc[rr].y = fmaf(hv.x, w0.y, acc[rr].y);
            acc[rr].z = fmaf(hv.x, w0.z, acc[rr].z);
            acc[rr].w = fmaf(hv.x, w0.w, acc[rr].w);
            acc[rr].x = fmaf(hv.y, w1.x, acc[rr].x);
            acc[rr].y = fmaf(hv.y, w1.y, acc[rr].y);
            acc[rr].z = fmaf(hv.y, w1.z, acc[rr].z);
            acc[rr].w = fmaf(hv.y, w1.w, acc[rr].w);
            acc[rr].x = fmaf(hv.z, w2.x, acc[rr].x);
            acc[rr].y = fmaf(hv.z, w2.y, acc[rr].y);
            acc[rr].z = fmaf(hv.z, w2.z, acc[rr].z);
            acc[rr].w = fmaf(hv.z, w2.w, acc[rr].w);
            acc[rr].x = fmaf(hv.w, w3.x, acc[rr].x);
            acc[rr].y = fmaf(hv.w, w3.y, acc[rr].y);
            acc[rr].z = fmaf(hv.w, w3.z, acc[rr].z);
            acc[rr].w = fmaf(hv.w, w3.w, acc[rr].w);
        }
    }
    float4 a1 = ((const float4*)A.a)[c0];
    float4 a2 = ((const float4*)A.a)[16 + c0];
    float tmax = -3.4e38f;
    #pragma unroll
    for (int rr = 0; rr < 4; ++rr) {
        int row = row0 + rbase + rr;
        ((float4*)A.Wh)[(size_t)row * 16 + c0] = acc[rr];
        float sv = acc[rr].x * a1.x + acc[rr].y * a1.y + acc[rr].z * a1.z + acc[rr].w * a1.w;
        float tv = acc[rr].x * a2.x + acc[rr].y * a2.y + acc[rr].z * a2.z + acc[rr].w * a2.w;
        #pragma unroll
        for (int off = 8; off; off >>= 1) {
            sv += __shfl_xor(sv, off, 64);
            tv += __shfl_xor(tv, off, 64);
        }
        if (c0 == 0) { A.s[row] = sv; A.t[row] = tv; }
        tmax = fmaxf(tmax, tv);
    }
    tmax = fmaxf(tmax, __shfl_xor(tmax, 16, 64));
    tmax = fmaxf(tmax, __shfl_xor(tmax, 32, 64));
    __syncthreads();
    float* wmax = (float*)sm4;
    if (lane == 0) wmax[wave] = tmax;
    __syncthreads();
    if (tid == 0)
        A.tblkmax[blk] = fmaxf(fmaxf(wmax[0], wmax[1]), fmaxf(wmax[2], wmax[3]));
}

// ---------- K2: LDS hist + pre-hist + scan + T + packed-key scatter ----------
// 24 blocks x 1024; slice = 1024 items/block. Full histogram (and before-slice
// histogram) built redundantly in LDS -> no global atomics anywhere.
__global__ __launch_bounds__(1024) void k2_sort(Args A) {
    __shared__ int hist[NBIN];                  // 32 KB
    __shared__ int pre[NBIN];                   // 32 KB
    __shared__ int wtot[16];
    __shared__ float fmax_[16];
    int tid = threadIdx.x, lane = tid & 63, wave = tid >> 6, blk = blockIdx.x;
    #pragma unroll
    for (int e = tid; e < NBIN; e += 1024) { hist[e] = 0; pre[e] = 0; }
    __syncthreads();
    #pragma unroll 4
    for (int e = tid; e < M; e += 1024) {
        float v = (e < N) ? A.t[e] : -A.s[e - N];
        atomicAdd(&hist[t_bin(v)], 1);
    }
    int my0 = blk * 1024;
    #pragma unroll 4
    for (int e = tid; e < my0; e += 1024) {
        float v = (e < N) ? A.t[e] : -A.s[e - N];
        atomicAdd(&pre[t_bin(v)], 1);
    }
    __syncthreads();
    int b0 = tid * 8;
    int c8[8]; int sum = 0;
    #pragma unroll
    for (int g = 0; g < 8; ++g) { c8[g] = sum; sum += hist[b0 + g]; }
    int inc = sum;
    #pragma unroll
    for (int off = 1; off < 64; off <<= 1) {
        int nb = __shfl_up(inc, off, 64);
        if (lane >= off) inc += nb;
    }
    if (lane == 63) wtot[wave] = inc;
    __syncthreads();
    int wbase = 0;
    #pragma unroll
    for (int w = 0; w < 16; ++w) wbase += (w < wave) ? wtot[w] : 0;
    int tstart = wbase + inc - sum;
    #pragma unroll
    for (int g = 0; g < 8; ++g) {
        int bs = tstart + c8[g];
        hist[b0 + g] = bs;
        pre[b0 + g] += bs;
        A.binstart[b0 + g] = bs;                // benign duplicate across blocks
    }
    if (tid == 0 && blk == 0) A.binstart[NBIN] = M;
    float m = (tid < 192) ? A.tblkmax[tid] : -3.4e38f;
    #pragma unroll
    for (int off = 32; off; off >>= 1) m = fmaxf(m, __shfl_xor(m, off, 64));
    if (lane == 0) fmax_[wave] = m;
    __syncthreads();
    if (tid == 0) {
        float mm = fmax_[0];
        #pragma unroll
        for (int w = 1; w < 16; ++w) mm = fmaxf(mm, fmax_[w]);
        A.Thdr[0] = mm;
    }
    __syncthreads();
    {   // exactly one item per thread (slice == blockDim)
        int e = my0 + tid;
        float v = (e < N) ? A.t[e] : -A.s[e - N];
        int pi = (e < N) ? (e + N) : (e - N);   // queries sort before equal keys
        int pos = atomicAdd(&pre[t_bin(v)], 1);
        A.vals64[pos] = ((unsigned long long)f_ord(v) << 32) | (unsigned)pi;
    }
}

// ---------- K3: exact in-bin rank, thread/position, u64 keys, 4-wide --------
__global__ __launch_bounds__(256) void k3_rank(Args A) {
    int p = blockIdx.x * 256 + threadIdx.x;
    unsigned long long kp = A.vals64[p];
    int b = (int)(kp >> (32 + BSHIFT));
    int lo = A.binstart[b], hi = A.binstart[b + 1];
    int cnt = 0;
    int q = lo;
    while (q < hi && (q & 3)) cnt += (int)(A.vals64[q++] < kp);
    int bend = q + ((hi - q) & ~3);
    #pragma unroll 2
    for (; q < bend; q += 4) {
        ulonglong2 u0 = *(const ulonglong2*)&A.vals64[q];
        ulonglong2 u1 = *(const ulonglong2*)&A.vals64[q + 2];
        cnt += (int)(u0.x < kp) + (int)(u0.y < kp)
             + (int)(u1.x < kp) + (int)(u1.y < kp);
    }
    while (q < hi) cnt += (int)(A.vals64[q++] < kp);
    int pi = (int)(unsigned)(kp & 0xffffffffu);
    A.tfin[lo + cnt] = ord_f((unsigned)(kp >> 32));
    A.idfin[lo + cnt] = (pi >= N) ? (pi - N) : (pi + N);
}

// ---------- K4: per-chunk (64 sorted items) key-sums, prefetched gather -----
__global__ __launch_bounds__(256) void k4_sums(Args A) {
    int tid = threadIdx.x, wave = tid >> 6, lane = tid & 63;
    int c = blockIdx.x * 4 + wave;              // 96 blocks -> 384 chunks
    float T = A.Thdr[0];
    float myval = A.tfin[c * 64 + lane];
    int myid = A.idfin[c * 64 + lane];
    float x[64];
    #pragma unroll
    for (int k = 0; k < 64; ++k) {              // 64 independent gathers
        int uid = __shfl(myid, k, 64);
        x[k] = (uid < N) ? A.Wh[(size_t)uid * DOUT + lane] : 0.f;
    }
    float av = 0.f, au = 0.f, svs = 0.f, sus = 0.f;
    #pragma unroll
    for (int k = 0; k < 64; ++k) {
        int uid = __shfl(myid, k, 64);
        if (uid < N) {
            float uval = __shfl(myval, k, 64);
            float wu = expf(uval - T);
            float wv = expf(0.2f * (uval - T));
            av = fmaf(wv, x[k], av); au = fmaf(wu, x[k], au);
            svs += wv; sus += wu;
        }
    }
    A.Vct[c * 64 + lane] = av;
    A.Uct[c * 64 + lane] = au;
    if (lane == 0) { A.vsc[c] = svs; A.usc[c] = sus; }
}

// ---------- K4b: wave-parallel forward-exclusive scans over chunks ----------
__global__ __launch_bounds__(256) void k4b_scan(Args A) {
    int tid = threadIdx.x, wave = tid >> 6, lane = tid & 63;
    int task = blockIdx.x * 4 + wave;           // 33 blocks -> 132 waves
    if (task >= 130) return;
    const float* src; float* dst; int stride, col = 0;
    if (task < 64)       { col = task;      src = A.Vct; dst = A.basevt; stride = 64; }
    else if (task < 128) { col = task - 64; src = A.Uct; dst = A.baseut; stride = 64; }
    else if (task == 128){ src = A.vsc; dst = A.basevs; stride = 1; }
    else                 { src = A.usc; dst = A.baseus; stride = 1; }
    float base = 0.f;
    for (int c0 = 0; c0 < NCHUNK; c0 += 64) {
        float xv = src[(c0 + lane) * stride + col];
        float inc = xv;
        #pragma unroll
        for (int off = 1; off < 64; off <<= 1) {
            float nb = __shfl_up(inc, off, 64);
            if (lane >= off) inc += nb;
        }
        dst[(c0 + lane) * stride + col] = base + inc - xv;
        base += __shfl(inc, 63, 64);
    }
    if (lane == 0) {
        if (task >= 64 && task < 128) A.utot[col] = base;   // U column total
        else if (task == 129)         A.utots[0] = base;    // U scalar total
    }
}

// ---------- K5: sweep with precomputed bases; queries emit output ----------
__global__ __launch_bounds__(256) void k5_apply(Args A) {
    int tid = threadIdx.x, wave = tid >> 6, lane = tid & 63;
    int c = blockIdx.x * 4 + wave;              // 384 chunks
    float T = A.Thdr[0];
    float myval = A.tfin[c * 64 + lane];
    int myid = A.idfin[c * 64 + lane];
    float x[64];
    #pragma unroll
    for (int k = 0; k < 64; ++k) {              // 64 independent gathers
        int uid = __shfl(myid, k, 64);
        x[k] = (uid < N) ? A.Wh[(size_t)uid * DOUT + lane] : 0.f;
    }
    float rv  = A.basevt[c * 64 + lane];
    float ru  = A.baseut[c * 64 + lane];
    float rvs = A.basevs[c];
    float rus = A.baseus[c];
    float tu  = A.utot[lane];
    float tus = A.utots[0];
    #pragma unroll
    for (int k = 0; k < 64; ++k) {
        float uval = __shfl(myval, k, 64);
        int uid = __shfl(myid, k, 64);
        if (uid < N) {                          // key: advance running sums
            float wu = expf(uval - T);
            float wv = expf(0.2f * (uval - T));
            rv = fmaf(wv, x[k], rv); ru = fmaf(wu, x[k], ru);
            rvs += wv; rus += wu;
        } else {                                // query: emit output row
            int i = uid - N;
            float si = -uval;
            float xx = si + T;
            float mm = fmaxf(xx, 0.2f * xx);
            float cp_ = expf(xx - mm);
            float cn_ = expf(0.2f * xx - mm);
            float num = cn_ * rv + cp_ * (tu - ru);
            float den = cn_ * rvs + cp_ * (tus - rus);
            float r = num / den;
            A.out[(size_t)i * DOUT + lane] = r > 0.f ? r : expm1f(r);
        }
    }
}

extern "C" void kernel_launch(void* const* d_in, const int* in_sizes, int n_in,
                              void* d_out, int out_size, void* d_ws, size_t ws_size,
                              hipStream_t stream) {
    float* ws = (float*)d_ws;
    size_t o = 0;
    Args A;
    A.h = (const float*)d_in[0];
    A.W = (const float*)d_in[1];
    A.a = (const float*)d_in[2];
    A.out = (float*)d_out;
    A.Wh      = ws + o; o += (size_t)N * DOUT;
    A.s       = ws + o; o += N;
    A.t       = ws + o; o += N;
    A.tblkmax = ws + o; o += 192;
    A.Thdr    = ws + o; o += 16;                // o now 16B-aligned (811216)
    A.vals64  = (unsigned long long*)(ws + o); o += 2 * (size_t)M;
    A.tfin    = ws + o; o += M;
    A.Vct     = ws + o; o += (size_t)NCHUNK * DOUT;
    A.Uct     = ws + o; o += (size_t)NCHUNK * DOUT;
    A.vsc     = ws + o; o += NCHUNK;
    A.usc     = ws + o; o += NCHUNK;
    A.basevt  = ws + o; o += (size_t)NCHUNK * DOUT;
    A.baseut  = ws + o; o += (size_t)NCHUNK * DOUT;
    A.basevs  = ws + o; o += NCHUNK;
    A.baseus  = ws + o; o += NCHUNK;
    A.utot    = ws + o; o += DOUT;
    A.utots   = ws + o; o += 16;
    A.idfin    = (int*)(ws + o); o += M;
    A.binstart = (int*)(ws + o); o += NBIN + 1;
    // ~4.3 MB total; no initialization required

    k1_gemm <<<N / 64, 256, 0, stream>>>(A);
    k2_sort <<<24, 1024, 0, stream>>>(A);
    k3_rank <<<M / 256, 256, 0, stream>>>(A);
    k4_sums <<<NCHUNK / 4, 256, 0, stream>>>(A);
    k4b_scan<<<33, 256, 0, stream>>>(A);
    k5_apply<<<NCHUNK / 4, 256, 0, stream>>>(A);
}